// Round 1
// 532.513 us; speedup vs baseline: 1.0100x; 1.0100x over previous
//
#include <hip/hip_runtime.h>

#define DD 192

// =======================================================================
// stage3_k: C[s,i] = sum_j A'[s,j] * W[i,j] + bias[i]
//   A' = A (LNL=0), LN(A) (LNL=1), relu(LN(A)) (LNL=2)
//   LN stats come from stats_in[3][8192] (3 colgroup banks, summed here).
//   EMIT: 0 none, 1 colsum (atomicAdd emit_buf[i] += sum_s C[s,i]),
//         2 stats  (emit_buf[cg*8192 + 2r] = row-sum, +1 = row-sumsq; non-atomic)
// Block: 256 thr = 8 tr x 32 tc; tile 32 rows x 64 cols; thread = 4r x 2c.
// Grid: 384 = 3 colgroups x 128 rowgroups.
// Inner loop: chunked-register A (2x float4 per row per 8-j chunk) so the
// LDS issue count is 384 ds_read/thread instead of 960.
// =======================================================================
template <int EMIT, int LNL>
__global__ __launch_bounds__(256) void stage3_k(
    const float* __restrict__ A, const float* __restrict__ W,
    const float* __restrict__ bias,
    const float* __restrict__ stats_in, const float* __restrict__ lng,
    const float* __restrict__ lnb,
    float* __restrict__ out, float* __restrict__ emit_buf) {
    __shared__ float At[32 * 200];   // row-major, stride 200 (bank-stride 8)
    __shared__ float WT[DD * 64];    // swizzled: word j*64 + ((ip + 2*(j&31)) & 63)
    __shared__ float ms[32], rs[32];
    __shared__ float csum[4 * 64];

    const int t = threadIdx.x;
    const int tr = t >> 5, tc = t & 31;
    const int b = blockIdx.x;
    const int cg = b % 3;
    const int c0 = cg * 64;
    const int r0 = (b / 3) * 32;

    if (LNL > 0) {
        if (t < 32) {
            int r = r0 + t;
            float s = stats_in[2 * r] + stats_in[8192 + 2 * r] + stats_in[16384 + 2 * r];
            float q = stats_in[2 * r + 1] + stats_in[8192 + 2 * r + 1]
                    + stats_in[16384 + 2 * r + 1];
            float mean = s * (1.f / 192.f);
            float var = q * (1.f / 192.f) - mean * mean;
            ms[t] = mean;
            rs[t] = rsqrtf(var + 1e-5f);
        }
        __syncthreads();
    }

    // ---- stage A tile (32 x 192), applying LN(+ReLU) on load ----
    {
        const float4* A4 = (const float4*)(A + (size_t)r0 * DD);
#pragma unroll
        for (int q = 0; q < 6; q++) {
            int f = t + 256 * q;               // < 1536
            int r = f / 48, jj = f - r * 48;
            float4 v = A4[f];
            if (LNL > 0) {
                float mean = ms[r], rstd = rs[r];
                float4 g4 = ((const float4*)lng)[jj];
                float4 b4 = ((const float4*)lnb)[jj];
                v.x = (v.x - mean) * rstd * g4.x + b4.x;
                v.y = (v.y - mean) * rstd * g4.y + b4.y;
                v.z = (v.z - mean) * rstd * g4.z + b4.z;
                v.w = (v.w - mean) * rstd * g4.w + b4.w;
                if (LNL == 2) {
                    v.x = fmaxf(v.x, 0.f); v.y = fmaxf(v.y, 0.f);
                    v.z = fmaxf(v.z, 0.f); v.w = fmaxf(v.w, 0.f);
                }
            }
            *(float4*)&At[r * 200 + 4 * jj] = v;
        }
    }
    // ---- stage W slice (64 x 192) transposed+swizzled ----
    {
        const float4* W4 = (const float4*)(W + (size_t)c0 * DD);
#pragma unroll
        for (int q = 0; q < 12; q++) {
            int f = t + 256 * q;               // < 3072
            int ip = f / 48, jj = f - ip * 48;
            float4 v = W4[f];
            int j0 = 4 * jj;
            WT[(j0 + 0) * 64 + ((ip + 2 * ((j0 + 0) & 31)) & 63)] = v.x;
            WT[(j0 + 1) * 64 + ((ip + 2 * ((j0 + 1) & 31)) & 63)] = v.y;
            WT[(j0 + 2) * 64 + ((ip + 2 * ((j0 + 2) & 31)) & 63)] = v.z;
            WT[(j0 + 3) * 64 + ((ip + 2 * ((j0 + 3) & 31)) & 63)] = v.w;
        }
    }

    const int i0 = c0 + 2 * tc;
    float bv0 = bias[i0], bv1 = bias[i0 + 1];
    float acc[4][2];
#pragma unroll
    for (int i = 0; i < 4; i++) { acc[i][0] = bv0; acc[i][1] = bv1; }
    __syncthreads();

    const int rbase = 4 * tr;
#pragma unroll 2
    for (int jc = 0; jc < DD; jc += 8) {
        float a_[4][8];
#pragma unroll
        for (int rr = 0; rr < 4; rr++) {
            float4 u = *(const float4*)&At[(rbase + rr) * 200 + jc];
            float4 v = *(const float4*)&At[(rbase + rr) * 200 + jc + 4];
            a_[rr][0] = u.x; a_[rr][1] = u.y; a_[rr][2] = u.z; a_[rr][3] = u.w;
            a_[rr][4] = v.x; a_[rr][5] = v.y; a_[rr][6] = v.z; a_[rr][7] = v.w;
        }
#pragma unroll
        for (int jj = 0; jj < 8; jj++) {
            const int j = jc + jj;
            int cs = (2 * tc + 2 * (j & 31)) & 63;
            float2 w2 = *(const float2*)&WT[j * 64 + cs];
            acc[0][0] = fmaf(a_[0][jj], w2.x, acc[0][0]);
            acc[0][1] = fmaf(a_[0][jj], w2.y, acc[0][1]);
            acc[1][0] = fmaf(a_[1][jj], w2.x, acc[1][0]);
            acc[1][1] = fmaf(a_[1][jj], w2.y, acc[1][1]);
            acc[2][0] = fmaf(a_[2][jj], w2.x, acc[2][0]);
            acc[2][1] = fmaf(a_[2][jj], w2.y, acc[2][1]);
            acc[3][0] = fmaf(a_[3][jj], w2.x, acc[3][0]);
            acc[3][1] = fmaf(a_[3][jj], w2.y, acc[3][1]);
        }
    }

#pragma unroll
    for (int i = 0; i < 4; i++) {
        int row = r0 + rbase + i;
        *(float2*)&out[(size_t)row * DD + i0] = make_float2(acc[i][0], acc[i][1]);
    }

    if (EMIT == 2) {
#pragma unroll
        for (int i = 0; i < 4; i++) {
            float s = acc[i][0] + acc[i][1];
            float q = acc[i][0] * acc[i][0] + acc[i][1] * acc[i][1];
#pragma unroll
            for (int m = 16; m >= 1; m >>= 1) {
                s += __shfl_xor(s, m);
                q += __shfl_xor(q, m);
            }
            if (tc == 0) {
                int r = r0 + rbase + i;
                emit_buf[cg * 8192 + 2 * r] = s;
                emit_buf[cg * 8192 + 2 * r + 1] = q;
            }
        }
    } else if (EMIT == 1) {
        float cs0 = acc[0][0] + acc[1][0] + acc[2][0] + acc[3][0];
        float cs1 = acc[0][1] + acc[1][1] + acc[2][1] + acc[3][1];
        cs0 += __shfl_xor(cs0, 32);   // fold tr-pair within wave
        cs1 += __shfl_xor(cs1, 32);
        int w = t >> 6;
        if ((t & 63) < 32) {
            csum[w * 64 + 2 * tc] = cs0;
            csum[w * 64 + 2 * tc + 1] = cs1;
        }
        __syncthreads();
        if (t < 64) {
            float s = csum[t] + csum[64 + t] + csum[128 + t] + csum[192 + t];
            atomicAdd(&emit_buf[c0 + t], s);
        }
    }
}

// =======================================================================
// hyper_k: combined hypernet weights, 32 AW-rows per block, coalesced.
// Grid 3456: b<1152 -> Wt, b<2304 -> Wc, else MoE chunk: one block owns
// rows k0..k0+31 for ALL 8 experts (serial e-loop over one LDS buffer),
// accumulates gate-weighted sum in registers, writes Wmoe non-atomically.
// =======================================================================
__global__ __launch_bounds__(256) void hyper_k(
    const float* __restrict__ tm_W, const float* __restrict__ tm_AW,
    const float* __restrict__ tm_Ab, const float* __restrict__ cm_W,
    const float* __restrict__ cm_AW, const float* __restrict__ cm_Ab,
    const float* __restrict__ ex_W, const float* __restrict__ ex_AW,
    const float* __restrict__ ex_Ab, const float* __restrict__ a0g,
    const float* __restrict__ gateg, float* __restrict__ Wt,
    float* __restrict__ Wc, float* __restrict__ Wmoe) {
    __shared__ float a0s[DD];
    __shared__ float rows[32 * 204];
    __shared__ float wb[32], ab[32], vals[32];
    __shared__ float gs[8];
    const int t = threadIdx.x;
    const int b = blockIdx.x;
    const int r = t >> 3, p = t & 7;
    if (t < DD) a0s[t] = a0g[t];

    if (b < 2304) {
        const float* AW; const float* WB; const float* AB; float* dst;
        int k0;
        if (b < 1152) { AW = tm_AW; WB = tm_W; AB = tm_Ab; dst = Wt; k0 = b * 32; }
        else          { AW = cm_AW; WB = cm_W; AB = cm_Ab; dst = Wc; k0 = (b - 1152) * 32; }
        if (t < 32) { wb[t] = WB[k0 + t]; ab[t] = AB[k0 + t]; }
        const float4* src4 = (const float4*)(AW + (size_t)k0 * DD);
#pragma unroll
        for (int q = 0; q < 6; q++) {
            int fidx = t + 256 * q;            // < 1536
            int rr = fidx / 48, jj = fidx - rr * 48;
            *(float4*)&rows[rr * 204 + 4 * jj] = src4[fidx];
        }
        __syncthreads();
        float acc = 0.f;
#pragma unroll
        for (int q = 0; q < 6; q++) {
            int jo = p * 24 + 4 * q;
            float4 w = *(const float4*)&rows[r * 204 + jo];
            float4 aa = *(const float4*)&a0s[jo];
            acc = fmaf(w.x, aa.x, acc); acc = fmaf(w.y, aa.y, acc);
            acc = fmaf(w.z, aa.z, acc); acc = fmaf(w.w, aa.w, acc);
        }
        acc += __shfl_xor(acc, 1);
        acc += __shfl_xor(acc, 2);
        acc += __shfl_xor(acc, 4);
        if (p == 0) vals[r] = acc + wb[r] + ab[r];
        __syncthreads();
        if (t < 32) dst[k0 + t] = vals[t];
    } else {
        const int k0 = (b - 2304) * 32;
        if (t < 8) gs[t] = gateg[t];
        float macc = 0.f;
        for (int e = 0; e < 8; e++) {
            __syncthreads();                   // rows/vals reuse + a0s/gs ready
            const float4* src4 =
                (const float4*)(ex_AW + (size_t)e * 36864 * DD + (size_t)k0 * DD);
#pragma unroll
            for (int q = 0; q < 6; q++) {
                int fidx = t + 256 * q;        // < 1536
                int rr = fidx / 48, jj = fidx - rr * 48;
                *(float4*)&rows[rr * 204 + 4 * jj] = src4[fidx];
            }
            __syncthreads();
            float acc = 0.f;
#pragma unroll
            for (int q = 0; q < 6; q++) {
                int jo = p * 24 + 4 * q;
                float4 w = *(const float4*)&rows[r * 204 + jo];
                float4 aa = *(const float4*)&a0s[jo];
                acc = fmaf(w.x, aa.x, acc); acc = fmaf(w.y, aa.y, acc);
                acc = fmaf(w.z, aa.z, acc); acc = fmaf(w.w, aa.w, acc);
            }
            acc += __shfl_xor(acc, 1);
            acc += __shfl_xor(acc, 2);
            acc += __shfl_xor(acc, 4);
            if (p == 0) vals[r] = acc;
            __syncthreads();
            if (t < 32) {
                float we = ex_W[(size_t)e * 36864 + k0 + t];
                float ae = ex_Ab[(size_t)e * 36864 + k0 + t];
                macc = fmaf(gs[e], vals[t] + we + ae, macc);
            }
        }
        if (t < 32) Wmoe[k0 + t] = macc;
    }
}

// =======================================================================
// feat2_k: a_pre[i] += sum_{j in chunk} xm[j]*(feat_W[k]+feat_AW[k,:]@xm+feat_Ab[k])
// =======================================================================
__global__ __launch_bounds__(256) void feat2_k(
    const float* __restrict__ feat_W, const float* __restrict__ feat_AW,
    const float* __restrict__ feat_Ab, const float* __restrict__ xm_sum,
    float* __restrict__ a_pre) {
    __shared__ float xms[DD];
    __shared__ float rows[32 * 204];
    __shared__ float wb[32], ab[32], vals[32];
    const int t = threadIdx.x;
    const int k0 = blockIdx.x * 32;
    if (t < DD) xms[t] = xm_sum[t] * (1.f / 4096.f);
    if (t < 32) { wb[t] = feat_W[k0 + t]; ab[t] = feat_Ab[k0 + t]; }
    const float4* src4 = (const float4*)(feat_AW + (size_t)k0 * DD);
#pragma unroll
    for (int q = 0; q < 6; q++) {
        int fidx = t + 256 * q;
        int r = fidx / 48, jj = fidx - r * 48;
        float4 v = src4[fidx];
        *(float4*)&rows[r * 204 + 4 * jj] = v;
    }
    __syncthreads();
    const int r = t >> 3, p = t & 7;
    float acc = 0.f;
#pragma unroll
    for (int q = 0; q < 6; q++) {
        int jo = p * 24 + 4 * q;
        float4 w = *(const float4*)&rows[r * 204 + jo];
        float4 aa = *(const float4*)&xms[jo];
        acc = fmaf(w.x, aa.x, acc); acc = fmaf(w.y, aa.y, acc);
        acc = fmaf(w.z, aa.z, acc); acc = fmaf(w.w, aa.w, acc);
    }
    acc += __shfl_xor(acc, 1);
    acc += __shfl_xor(acc, 2);
    acc += __shfl_xor(acc, 4);
    if (p == 0) vals[r] = acc + wb[r] + ab[r];
    __syncthreads();
    const int j0 = k0 % DD;   // chunk of 32 stays within one output i
    if (t < 32) {
        float c = vals[t] * xms[j0 + t];
#pragma unroll
        for (int m = 16; m >= 1; m >>= 1) c += __shfl_xor(c, m);
        if (t == 0) atomicAdd(&a_pre[k0 / DD], c);
    }
}

// =======================================================================
// vec_k: a0 = LN(a_pre + feat_b); gate = softmax(a0@gate_W^T + gate_b);
//        b_moe = sum_e gate[e]*ex_b[e,:]
// Gate logits via wave shuffle reductions (no LDS atomics).
// =======================================================================
__global__ __launch_bounds__(192) void vec_k(
    const float* __restrict__ a_pre, const float* __restrict__ feat_b,
    const float* __restrict__ an_g, const float* __restrict__ an_b,
    const float* __restrict__ gate_W, const float* __restrict__ gate_b,
    const float* __restrict__ ex_b, float* __restrict__ a0g,
    float* __restrict__ gateg, float* __restrict__ b_moe) {
    __shared__ float red[6];
    __shared__ float gred[24];   // 3 waves x 8 experts
    __shared__ float lgs[8];
    const int t = threadIdx.x;
    const int w = t >> 6;
    float v = a_pre[t] + feat_b[t];
    float s = v, q = v * v;
#pragma unroll
    for (int m = 32; m >= 1; m >>= 1) {
        s += __shfl_xor(s, m);
        q += __shfl_xor(q, m);
    }
    if ((t & 63) == 0) { red[w] = s; red[3 + w] = q; }
    __syncthreads();
    float S = red[0] + red[1] + red[2];
    float Q = red[3] + red[4] + red[5];
    float mean = S * (1.f / 192.f);
    float var = Q * (1.f / 192.f) - mean * mean;
    float rstd = rsqrtf(var + 1e-5f);
    float a0v = (v - mean) * rstd * an_g[t] + an_b[t];
    a0g[t] = a0v;
#pragma unroll
    for (int e = 0; e < 8; e++) {
        float x = a0v * gate_W[e * DD + t];
#pragma unroll
        for (int m = 32; m >= 1; m >>= 1) x += __shfl_xor(x, m);
        if ((t & 63) == 0) gred[w * 8 + e] = x;
    }
    __syncthreads();
    if (t < 8) lgs[t] = gred[t] + gred[8 + t] + gred[16 + t] + gate_b[t];
    __syncthreads();
    if (t == 0) {
        float mx = lgs[0];
        for (int e = 1; e < 8; e++) mx = fmaxf(mx, lgs[e]);
        float sum = 0.f, ex[8];
        for (int e = 0; e < 8; e++) { ex[e] = expf(lgs[e] - mx); sum += ex[e]; }
        for (int e = 0; e < 8; e++) lgs[e] = ex[e] / sum;
    }
    __syncthreads();
    if (t < 8) gateg[t] = lgs[t];
    float bm = 0.f;
#pragma unroll
    for (int e = 0; e < 8; e++) bm = fmaf(lgs[e], ex_b[e * DD + t], bm);
    b_moe[t] = bm;
}

// =======================================================================
extern "C" void kernel_launch(void* const* d_in, const int* in_sizes, int n_in,
                              void* d_out, int out_size, void* d_ws, size_t ws_size,
                              hipStream_t stream) {
    (void)in_sizes; (void)n_in; (void)out_size; (void)ws_size;
    const float* x       = (const float*)d_in[0];
    const float* W_in    = (const float*)d_in[1];
    const float* b_in    = (const float*)d_in[2];
    const float* feat_W  = (const float*)d_in[3];
    const float* feat_b  = (const float*)d_in[4];
    const float* feat_AW = (const float*)d_in[5];
    const float* feat_Ab = (const float*)d_in[6];
    const float* an_g    = (const float*)d_in[7];
    const float* an_b    = (const float*)d_in[8];
    const float* tm_W    = (const float*)d_in[9];
    const float* tm_b    = (const float*)d_in[10];
    const float* tm_AW   = (const float*)d_in[11];
    const float* tm_Ab   = (const float*)d_in[12];
    const float* tn_g    = (const float*)d_in[13];
    const float* tn_b    = (const float*)d_in[14];
    const float* cm_W    = (const float*)d_in[15];
    const float* cm_b    = (const float*)d_in[16];
    const float* cm_AW   = (const float*)d_in[17];
    const float* cm_Ab   = (const float*)d_in[18];
    const float* cn_g    = (const float*)d_in[19];
    const float* cn_b    = (const float*)d_in[20];
    const float* pm_W    = (const float*)d_in[21];
    const float* pm_b    = (const float*)d_in[22];
    const float* gate_W  = (const float*)d_in[23];
    const float* gate_b  = (const float*)d_in[24];
    const float* ex_W    = (const float*)d_in[25];
    const float* ex_b    = (const float*)d_in[26];
    const float* ex_AW   = (const float*)d_in[27];
    const float* ex_Ab   = (const float*)d_in[28];
    const float* mn_g    = (const float*)d_in[29];
    const float* mn_b    = (const float*)d_in[30];
    const float* out_W   = (const float*)d_in[31];
    const float* out_b   = (const float*)d_in[32];

    float* ws = (float*)d_ws;
    float* B0     = ws;                 // 786432
    float* B1     = ws + 786432;        // 786432
    float* xm_sum = ws + 1572864;       // 192    [zeroed]
    float* a_pre  = ws + 1573056;       // 192    [zeroed]
    float* Wmoe   = ws + 1573248;       // 36864  (fully written by hyper_k)
    float* Wt     = ws + 1610112;       // 36864
    float* Wc     = ws + 1646976;       // 36864
    float* st1    = ws + 1683840;       // 3*8192 (not zeroed; fully written)
    float* st2    = ws + 1708416;       // 3*8192
    float* st3    = ws + 1732992;       // 3*8192
    float* a0     = ws + 1757568;       // 192
    float* gate   = ws + 1757760;       // 8
    float* b_moe  = ws + 1757768;       // 192

    // zero xm_sum + a_pre only (Wmoe no longer accumulated atomically)
    hipMemsetAsync(xm_sum, 0, (size_t)384 * sizeof(float), stream);

    // S1: h = x @ W_in^T + b_in ; colsum -> xm_sum        (x -> B0)
    stage3_k<1, 0><<<384, 256, 0, stream>>>(x, W_in, b_in, nullptr, nullptr, nullptr,
                                            B0, xm_sum);
    feat2_k<<<1152, 256, 0, stream>>>(feat_W, feat_AW, feat_Ab, xm_sum, a_pre);
    vec_k<<<1, 192, 0, stream>>>(a_pre, feat_b, an_g, an_b, gate_W, gate_b, ex_b,
                                 a0, gate, b_moe);
    hyper_k<<<3456, 256, 0, stream>>>(tm_W, tm_AW, tm_Ab, cm_W, cm_AW, cm_Ab,
                                      ex_W, ex_AW, ex_Ab, a0, gate, Wt, Wc, Wmoe);
    // S2: tpre = h @ Wt^T + tm_b ; stats -> st1           (B0 -> B1)
    stage3_k<2, 0><<<384, 256, 0, stream>>>(B0, Wt, tm_b, nullptr, nullptr, nullptr,
                                            B1, st1);
    // S3: cpre = LN_tn(tpre) @ Wc^T + cm_b ; stats -> st2 (B1 -> B0)
    stage3_k<2, 1><<<384, 256, 0, stream>>>(B1, Wc, cm_b, st1, tn_g, tn_b, B0, st2);
    // S4: m = LN_cn(cpre) @ pm_W^T + pm_b                 (B0 -> B1)
    stage3_k<0, 1><<<384, 256, 0, stream>>>(B0, pm_W, pm_b, st2, cn_g, cn_b, B1, nullptr);
    // S5: eopre = m @ Wmoe^T + b_moe ; stats -> st3       (B1 -> B0)
    stage3_k<2, 0><<<384, 256, 0, stream>>>(B1, Wmoe, b_moe, nullptr, nullptr, nullptr,
                                            B0, st3);
    // S6: out = relu(LN_mn(eopre)) @ out_W^T + out_b      (B0 -> d_out)
    stage3_k<0, 2><<<384, 256, 0, stream>>>(B0, out_W, out_b, st3, mn_g, mn_b,
                                            (float*)d_out, nullptr);
}